// Round 1
// baseline (892.645 us; speedup 1.0000x reference)
//
#include <hip/hip_runtime.h>
#include <math.h>

#define B_ 16
#define S_ 6
#define E_ 256
#define NH_ 8
#define HD_ 32
#define HW_ 4096            // 64*64
#define ROWS_ (B_*S_*E_)    // 24576
#define SE_ (S_*E_)         // 1536
#define CROSS_N_ ((size_t)ROWS_*HW_)  // 100663296

// ---------------- Kernel 1: spatial mean + temporal pos ----------------
// one block (256 thr) per (b,s,e) row of 4096 contiguous floats
__global__ __launch_bounds__(256) void pool_kernel(
    const float* __restrict__ ff, const float* __restrict__ tpos,
    float* __restrict__ g)
{
    const int row = blockIdx.x;                    // b*1536 + s*256 + e
    const float4* p = (const float4*)(ff + (size_t)row * HW_);
    float sum = 0.f;
    #pragma unroll
    for (int i = 0; i < 4; ++i) {
        float4 v = p[threadIdx.x + i * 256];
        sum += v.x + v.y + v.z + v.w;
    }
    // wave64 reduce
    #pragma unroll
    for (int off = 32; off > 0; off >>= 1)
        sum += __shfl_down(sum, off, 64);
    __shared__ float part[4];
    if ((threadIdx.x & 63) == 0) part[threadIdx.x >> 6] = sum;
    __syncthreads();
    if (threadIdx.x == 0) {
        float tot = part[0] + part[1] + part[2] + part[3];
        g[row] = tot * (1.0f / HW_) + tpos[row % SE_];
    }
}

// ---------------- Kernel 2: tiny multi-head attention ----------------
// one block per batch element; 256 threads (thread = embed channel e)
__global__ __launch_bounds__(256) void attn_kernel(
    const float* __restrict__ g,
    const float* __restrict__ Wq, const float* __restrict__ bq,
    const float* __restrict__ Wk, const float* __restrict__ bk,
    const float* __restrict__ Wv, const float* __restrict__ bv,
    const float* __restrict__ Wo, const float* __restrict__ bo,
    float* __restrict__ out_g, float* __restrict__ attn_out)
{
    __shared__ float sg[S_][E_], sq[S_][E_], sk[S_][E_], sv[S_][E_], satd[S_][E_];
    __shared__ float satt[NH_][S_][S_];
    const int b = blockIdx.x;
    const int e = threadIdx.x;

    #pragma unroll
    for (int s = 0; s < S_; ++s)
        sg[s][e] = g[(size_t)b * SE_ + s * E_ + e];
    __syncthreads();

    // q,k,v projections: thread e computes channel e for all s
    {
        const float* wq = Wq + (size_t)e * E_;
        const float* wk = Wk + (size_t)e * E_;
        const float* wv = Wv + (size_t)e * E_;
        #pragma unroll
        for (int s = 0; s < S_; ++s) {
            float aq = bq[e], ak = bk[e], av = bv[e];
            for (int i = 0; i < E_; ++i) {
                float gv = sg[s][i];
                aq = fmaf(gv, wq[i], aq);
                ak = fmaf(gv, wk[i], ak);
                av = fmaf(gv, wv[i], av);
            }
            sq[s][e] = aq; sk[s][e] = ak; sv[s][e] = av;
        }
    }
    __syncthreads();

    // scores with causal mask (288 = 8*6*6 items)
    const float inv_scale = rsqrtf((float)HD_);
    for (int idx = e; idx < NH_ * S_ * S_; idx += 256) {
        int h = idx / (S_ * S_);
        int r = idx % (S_ * S_);
        int s = r / S_, t = r % S_;
        float sc = -INFINITY;
        if (t <= s) {
            sc = 0.f;
            #pragma unroll
            for (int d = 0; d < HD_; ++d)
                sc = fmaf(sq[s][h * HD_ + d], sk[t][h * HD_ + d], sc);
            sc *= inv_scale;
        }
        satt[h][s][t] = sc;
    }
    __syncthreads();

    // row softmax: 48 rows
    if (e < NH_ * S_) {
        int h = e / S_, s = e % S_;
        float m = -INFINITY;
        for (int t = 0; t <= s; ++t) m = fmaxf(m, satt[h][s][t]);
        float ex[S_], sum = 0.f;
        for (int t = 0; t <= s; ++t) { ex[t] = expf(satt[h][s][t] - m); sum += ex[t]; }
        float inv = 1.0f / sum;
        for (int t = 0; t < S_; ++t)
            satt[h][s][t] = (t <= s) ? ex[t] * inv : 0.0f;
    }
    __syncthreads();

    // attended[s][e] = sum_t attn[h][s][t] * v[t][e],  h = e>>5
    {
        const int h = e >> 5;
        #pragma unroll
        for (int s = 0; s < S_; ++s) {
            float a = 0.f;
            for (int t = 0; t <= s; ++t)
                a = fmaf(satt[h][s][t], sv[t][e], a);
            satd[s][e] = a;
        }
    }
    __syncthreads();

    // output projection
    {
        const float* wo = Wo + (size_t)e * E_;
        #pragma unroll
        for (int s = 0; s < S_; ++s) {
            float o = bo[e];
            for (int i = 0; i < E_; ++i)
                o = fmaf(satd[s][i], wo[i], o);
            out_g[(size_t)b * SE_ + s * E_ + e] = o;
        }
    }

    // emit attn tuple output [B, NH, S, S]
    for (int idx = e; idx < NH_ * S_ * S_; idx += 256) {
        int h = idx / (S_ * S_);
        int r = idx % (S_ * S_);
        attn_out[(size_t)b * (NH_ * S_ * S_) + idx] = satt[h][r / S_][r % S_];
    }
}

// ---------------- Kernel 3: broadcast add ----------------
// one block per (b,s,e) row; uniform scalar add, float4 copy
__global__ __launch_bounds__(256) void add_kernel(
    const float* __restrict__ ff, const float* __restrict__ out_g,
    float* __restrict__ cross)
{
    const int row = blockIdx.x;
    const float add = out_g[row];      // wave-uniform -> scalar load
    const float4* p = (const float4*)(ff + (size_t)row * HW_);
    float4* q = (float4*)(cross + (size_t)row * HW_);
    #pragma unroll
    for (int i = 0; i < 4; ++i) {
        float4 v = p[threadIdx.x + i * 256];
        v.x += add; v.y += add; v.z += add; v.w += add;
        q[threadIdx.x + i * 256] = v;
    }
}

extern "C" void kernel_launch(void* const* d_in, const int* in_sizes, int n_in,
                              void* d_out, int out_size, void* d_ws, size_t ws_size,
                              hipStream_t stream) {
    const float* ff   = (const float*)d_in[0];
    const float* Wq   = (const float*)d_in[1];
    const float* bq   = (const float*)d_in[2];
    const float* Wk   = (const float*)d_in[3];
    const float* bk   = (const float*)d_in[4];
    const float* Wv   = (const float*)d_in[5];
    const float* bv   = (const float*)d_in[6];
    const float* Wo   = (const float*)d_in[7];
    const float* bo   = (const float*)d_in[8];
    const float* tpos = (const float*)d_in[9];

    float* out   = (float*)d_out;
    float* g     = (float*)d_ws;        // 24576 floats
    float* out_g = g + ROWS_;           // 24576 floats

    float* cross    = out;              // 100663296 floats
    float* attn_out = out + CROSS_N_;   // 4608 floats

    pool_kernel<<<ROWS_, 256, 0, stream>>>(ff, tpos, g);
    attn_kernel<<<B_, 256, 0, stream>>>(g, Wq, bq, Wk, bk, Wv, bv, Wo, bo,
                                        out_g, attn_out);
    add_kernel<<<ROWS_, 256, 0, stream>>>(ff, out_g, cross);
}